// Round 1
// baseline (246.220 us; speedup 1.0000x reference)
//
#include <hip/hip_runtime.h>

typedef short bf16x8 __attribute__((ext_vector_type(8)));
typedef float f32x4 __attribute__((ext_vector_type(4)));

__device__ __forceinline__ unsigned short f2bf(float f) {
    unsigned int u = __builtin_bit_cast(unsigned int, f);
    u = (u + 0x7FFFu + ((u >> 16) & 1u)) >> 16;
    return (unsigned short)u;
}
__device__ __forceinline__ float bf2f(unsigned short h) {
    unsigned int u = ((unsigned int)h) << 16;
    return __builtin_bit_cast(float, u);
}

// ---------------------------------------------------------------------------
// Prep: permute x (B,T,N,Dm) -> Xbf rows r = bn*128+t, bn = b*64+n; fp32->bf16
// 1,048,576 threads, 4 elems each.
__global__ __launch_bounds__(256) void k_prep_x(const float* __restrict__ x,
                                                unsigned int* __restrict__ Xbf2) {
    int tid = blockIdx.x * 256 + threadIdx.x;
    int c4 = tid & 63;      // group of 4 columns
    int r  = tid >> 6;      // output row
    int t = r & 127, bn = r >> 7;
    int n = bn & 63, b = bn >> 6;
    const float4 v = *((const float4*)(x + ((((size_t)(b * 128 + t)) * 64 + n) << 8)) + c4);
    uint2 o;
    o.x = (unsigned int)f2bf(v.x) | ((unsigned int)f2bf(v.y) << 16);
    o.y = (unsigned int)f2bf(v.z) | ((unsigned int)f2bf(v.w) << 16);
    *((uint2*)(Xbf2 + ((size_t)r << 7)) + c4) = o;
}

// Generic fp32 -> bf16 convert, 4 elements/thread (count % 4 == 0).
__global__ __launch_bounds__(256) void k_f2bf(const float* __restrict__ in,
                                              unsigned int* __restrict__ out, int n4) {
    int tid = blockIdx.x * 256 + threadIdx.x;
    if (tid >= n4) return;
    float4 v = ((const float4*)in)[tid];
    uint2 o;
    o.x = (unsigned int)f2bf(v.x) | ((unsigned int)f2bf(v.y) << 16);
    o.y = (unsigned int)f2bf(v.z) | ((unsigned int)f2bf(v.w) << 16);
    ((uint2*)out)[tid] = o;
}

// ---------------------------------------------------------------------------
// GEMM1: xz[16384 x 1024] = Xbf[16384 x 256] @ W_in_bf[1024 x 256]^T
// block = 4 waves; wave w: rows [blockIdx.x*256 + w*64, +64), cols [blockIdx.y*64, +64)
// cols < 512 -> xp (bf16), cols >= 512 -> z (bf16)
__global__ __launch_bounds__(256, 2) void k_gemm1(const unsigned short* __restrict__ A,
                                                  const unsigned short* __restrict__ Bw,
                                                  unsigned short* __restrict__ xp,
                                                  unsigned short* __restrict__ z) {
    const int w = threadIdx.x >> 6, l = threadIdx.x & 63;
    const int lr = l & 15, lg = l >> 4;
    const int row0 = blockIdx.x * 256 + w * 64;
    const int n0 = blockIdx.y * 64;
    f32x4 acc[4][4] = {};
    for (int k0 = 0; k0 < 256; k0 += 32) {
        const int ka = k0 + lg * 8;
        bf16x8 a[4], b[4];
        #pragma unroll
        for (int mi = 0; mi < 4; ++mi)
            a[mi] = *(const bf16x8*)(A + (size_t)(row0 + mi * 16 + lr) * 256 + ka);
        #pragma unroll
        for (int ni = 0; ni < 4; ++ni)
            b[ni] = *(const bf16x8*)(Bw + (size_t)(n0 + ni * 16 + lr) * 256 + ka);
        #pragma unroll
        for (int mi = 0; mi < 4; ++mi)
            #pragma unroll
            for (int ni = 0; ni < 4; ++ni)
                acc[mi][ni] = __builtin_amdgcn_mfma_f32_16x16x32_bf16(a[mi], b[ni], acc[mi][ni], 0, 0, 0);
    }
    const bool isz = (n0 >= 512);
    unsigned short* dst = isz ? z : xp;
    const int c0 = isz ? (n0 - 512) : n0;
    #pragma unroll
    for (int mi = 0; mi < 4; ++mi)
        #pragma unroll
        for (int r = 0; r < 4; ++r) {
            const int row = row0 + mi * 16 + lg * 4 + r;
            #pragma unroll
            for (int ni = 0; ni < 4; ++ni)
                dst[(size_t)row * 512 + c0 + ni * 16 + lr] = f2bf(acc[mi][ni][r]);
        }
}

// ---------------------------------------------------------------------------
// Depthwise causal conv(4) + bias + SiLU. One thread per (bn, d), serial in t.
__global__ __launch_bounds__(256) void k_conv(const unsigned short* __restrict__ xp,
                                              const float* __restrict__ Wc,
                                              const float* __restrict__ bc,
                                              unsigned short* __restrict__ ub) {
    const int tid = blockIdx.x * 256 + threadIdx.x;
    const int d = tid & 511, bn = tid >> 9;
    const float w0 = Wc[d * 4 + 0], w1 = Wc[d * 4 + 1], w2 = Wc[d * 4 + 2], w3 = Wc[d * 4 + 3];
    const float bias = bc[d];
    const unsigned short* src = xp + (size_t)bn * 65536 + d;
    unsigned short* dst = ub + (size_t)bn * 65536 + d;
    float x0 = 0.f, x1 = 0.f, x2 = 0.f;
    float x3 = bf2f(src[0]);
    for (int t = 0; t < 128; ++t) {
        float xn = (t < 127) ? bf2f(src[(t + 1) * 512]) : 0.f;
        float a = bias + x0 * w0 + x1 * w1 + x2 * w2 + x3 * w3;
        float u = a / (1.f + __expf(-a));
        dst[t * 512] = f2bf(u);
        x0 = x1; x1 = x2; x2 = x3; x3 = xn;
    }
}

// ---------------------------------------------------------------------------
// x_dbl[16384 x 48] = u_bf[16384 x 512] @ W_xproj_bf[48 x 512]^T  (fp32 out)
__global__ __launch_bounds__(256, 2) void k_xproj(const unsigned short* __restrict__ U,
                                                  const unsigned short* __restrict__ Wb,
                                                  float* __restrict__ xdbl) {
    const int w = threadIdx.x >> 6, l = threadIdx.x & 63;
    const int lr = l & 15, lg = l >> 4;
    const int row0 = blockIdx.x * 256 + w * 64;
    f32x4 acc[4][3] = {};
    for (int k0 = 0; k0 < 512; k0 += 32) {
        const int ka = k0 + lg * 8;
        bf16x8 a[4], b[3];
        #pragma unroll
        for (int mi = 0; mi < 4; ++mi)
            a[mi] = *(const bf16x8*)(U + (size_t)(row0 + mi * 16 + lr) * 512 + ka);
        #pragma unroll
        for (int ni = 0; ni < 3; ++ni)
            b[ni] = *(const bf16x8*)(Wb + (size_t)(ni * 16 + lr) * 512 + ka);
        #pragma unroll
        for (int mi = 0; mi < 4; ++mi)
            #pragma unroll
            for (int ni = 0; ni < 3; ++ni)
                acc[mi][ni] = __builtin_amdgcn_mfma_f32_16x16x32_bf16(a[mi], b[ni], acc[mi][ni], 0, 0, 0);
    }
    #pragma unroll
    for (int mi = 0; mi < 4; ++mi)
        #pragma unroll
        for (int r = 0; r < 4; ++r) {
            const int row = row0 + mi * 16 + lg * 4 + r;
            #pragma unroll
            for (int ni = 0; ni < 3; ++ni)
                xdbl[(size_t)row * 48 + ni * 16 + lr] = acc[mi][ni][r];
        }
}

// ---------------------------------------------------------------------------
// Selective scan. One thread per (bn, d). Computes dt = softplus(dt_raw@W_dt^T + b_dt)
// on the fly, A = -exp(A_log), 16-state recurrence, epilogue (y + u*D)*silu(z) -> bf16.
__global__ __launch_bounds__(256) void k_scan(const float* __restrict__ xdbl,
                                              const unsigned short* __restrict__ ub,
                                              const unsigned short* __restrict__ zb,
                                              const float* __restrict__ W_dt,
                                              const float* __restrict__ b_dt,
                                              const float* __restrict__ A_log,
                                              const float* __restrict__ Dp,
                                              unsigned short* __restrict__ yb) {
    const int tid = blockIdx.x * 256 + threadIdx.x;
    const int d = tid & 511, bn = tid >> 9;
    float A[16], Wd[16], h[16];
    #pragma unroll
    for (int s = 0; s < 16; ++s) {
        A[s] = -__expf(A_log[d * 16 + s]);
        Wd[s] = W_dt[d * 16 + s];
        h[s] = 0.f;
    }
    const float bias = b_dt[d], dpar = Dp[d];
    const float* xr = xdbl + (size_t)bn * 128 * 48;
    const unsigned short* up = ub + (size_t)bn * 65536 + d;
    const unsigned short* zp = zb + (size_t)bn * 65536 + d;
    unsigned short* yp = yb + (size_t)bn * 65536 + d;
    float uv = bf2f(up[0]), zv = bf2f(zp[0]);
    for (int t = 0; t < 128; ++t) {
        float un = 0.f, zn = 0.f;
        if (t < 127) { un = bf2f(up[(t + 1) * 512]); zn = bf2f(zp[(t + 1) * 512]); }
        const float* xrow = xr + t * 48;
        float dl = bias;
        #pragma unroll
        for (int r = 0; r < 16; ++r) dl += xrow[r] * Wd[r];
        float dt = (dl > 20.f) ? dl : log1pf(__expf(dl));
        float du = dt * uv;
        float y = 0.f;
        #pragma unroll
        for (int s = 0; s < 16; ++s) {
            float dA = __expf(dt * A[s]);
            h[s] = h[s] * dA + du * xrow[16 + s];
            y += h[s] * xrow[32 + s];
        }
        float yf = y + uv * dpar;
        yf *= zv / (1.f + __expf(-zv));
        yp[t * 512] = f2bf(yf);
        uv = un; zv = zn;
    }
}

// ---------------------------------------------------------------------------
// out = LayerNorm( y_bf[16384 x 512] @ W_out_bf[256 x 512]^T ) with permuted store.
// block = 4 waves, 32 rows x 256 cols (wave w owns cols [w*64, +64)).
__global__ __launch_bounds__(256, 2) void k_out_ln(const unsigned short* __restrict__ Y,
                                                   const unsigned short* __restrict__ Wb,
                                                   const float* __restrict__ gamma,
                                                   const float* __restrict__ beta,
                                                   float* __restrict__ out) {
    __shared__ float s_sum[32], s_sq[32];
    const int w = threadIdx.x >> 6, l = threadIdx.x & 63;
    const int lr = l & 15, lg = l >> 4;
    const int row0 = blockIdx.x * 32;
    const int n0 = w * 64;
    f32x4 acc[2][4] = {};
    for (int k0 = 0; k0 < 512; k0 += 32) {
        const int ka = k0 + lg * 8;
        bf16x8 a[2], b[4];
        #pragma unroll
        for (int mi = 0; mi < 2; ++mi)
            a[mi] = *(const bf16x8*)(Y + (size_t)(row0 + mi * 16 + lr) * 512 + ka);
        #pragma unroll
        for (int ni = 0; ni < 4; ++ni)
            b[ni] = *(const bf16x8*)(Wb + (size_t)(n0 + ni * 16 + lr) * 512 + ka);
        #pragma unroll
        for (int mi = 0; mi < 2; ++mi)
            #pragma unroll
            for (int ni = 0; ni < 4; ++ni)
                acc[mi][ni] = __builtin_amdgcn_mfma_f32_16x16x32_bf16(a[mi], b[ni], acc[mi][ni], 0, 0, 0);
    }
    if (threadIdx.x < 32) { s_sum[threadIdx.x] = 0.f; s_sq[threadIdx.x] = 0.f; }
    __syncthreads();
    #pragma unroll
    for (int mi = 0; mi < 2; ++mi)
        #pragma unroll
        for (int r = 0; r < 4; ++r) {
            float s = 0.f, q = 0.f;
            #pragma unroll
            for (int ni = 0; ni < 4; ++ni) { float v = acc[mi][ni][r]; s += v; q += v * v; }
            #pragma unroll
            for (int m = 1; m < 16; m <<= 1) { s += __shfl_xor(s, m, 64); q += __shfl_xor(q, m, 64); }
            if (lr == 0) {
                atomicAdd(&s_sum[mi * 16 + lg * 4 + r], s);
                atomicAdd(&s_sq[mi * 16 + lg * 4 + r], q);
            }
        }
    __syncthreads();
    float g[4], be[4];
    #pragma unroll
    for (int ni = 0; ni < 4; ++ni) {
        g[ni] = gamma[n0 + ni * 16 + lr];
        be[ni] = beta[n0 + ni * 16 + lr];
    }
    #pragma unroll
    for (int mi = 0; mi < 2; ++mi)
        #pragma unroll
        for (int r = 0; r < 4; ++r) {
            const int rl = mi * 16 + lg * 4 + r;
            const int row = row0 + rl;
            const float mu = s_sum[rl] * (1.f / 256.f);
            const float var = s_sq[rl] * (1.f / 256.f) - mu * mu;
            const float rs = rsqrtf(var + 1e-5f);
            const int t = row & 127, bn = row >> 7;
            const int nn = bn & 63, bb = bn >> 6;
            float* orow = out + ((((size_t)(bb * 128 + t)) * 64 + nn) << 8);
            #pragma unroll
            for (int ni = 0; ni < 4; ++ni)
                orow[n0 + ni * 16 + lr] = (acc[mi][ni][r] - mu) * rs * g[ni] + be[ni];
        }
}

// ---------------------------------------------------------------------------
extern "C" void kernel_launch(void* const* d_in, const int* in_sizes, int n_in,
                              void* d_out, int out_size, void* d_ws, size_t ws_size,
                              hipStream_t stream) {
    const float* x      = (const float*)d_in[0];
    const float* W_in   = (const float*)d_in[1];
    const float* W_conv = (const float*)d_in[2];
    const float* b_conv = (const float*)d_in[3];
    const float* W_xprj = (const float*)d_in[4];
    const float* W_dt   = (const float*)d_in[5];
    const float* b_dt   = (const float*)d_in[6];
    const float* A_log  = (const float*)d_in[7];
    const float* D_par  = (const float*)d_in[8];
    const float* W_out  = (const float*)d_in[9];
    const float* gamma  = (const float*)d_in[10];
    const float* beta   = (const float*)d_in[11];
    float* out = (float*)d_out;

    char* ws = (char*)d_ws;
    size_t off = 0;
    auto alloc = [&](size_t bytes) -> void* {
        void* p = ws + off;
        off += (bytes + 255) & ~(size_t)255;
        return p;
    };
    unsigned short* Xbf   = (unsigned short*)alloc(16384ull * 256 * 2);  // 8.4 MB
    unsigned short* Winb  = (unsigned short*)alloc(1024ull * 256 * 2);
    unsigned short* Wxpb  = (unsigned short*)alloc(48ull * 512 * 2);
    unsigned short* Woutb = (unsigned short*)alloc(256ull * 512 * 2);
    unsigned short* xp    = (unsigned short*)alloc(16384ull * 512 * 2);  // 16.8 MB
    unsigned short* zb    = (unsigned short*)alloc(16384ull * 512 * 2);
    unsigned short* ub    = (unsigned short*)alloc(16384ull * 512 * 2);
    float*          xdbl  = (float*)alloc(16384ull * 48 * 4);
    unsigned short* yb    = (unsigned short*)alloc(16384ull * 512 * 2);
    if (off > ws_size) return;  // workspace too small: fail loudly (zeros out)

    k_prep_x<<<4096, 256, 0, stream>>>(x, (unsigned int*)Xbf);
    k_f2bf<<<256, 256, 0, stream>>>(W_in, (unsigned int*)Winb, 65536);
    k_f2bf<<<24, 256, 0, stream>>>(W_xprj, (unsigned int*)Wxpb, 6144);
    k_f2bf<<<128, 256, 0, stream>>>(W_out, (unsigned int*)Woutb, 32768);
    k_gemm1<<<dim3(64, 16), 256, 0, stream>>>(Xbf, Winb, xp, zb);
    k_conv<<<256, 256, 0, stream>>>(xp, W_conv, b_conv, ub);
    k_xproj<<<64, 256, 0, stream>>>(ub, Wxpb, xdbl);
    k_scan<<<256, 256, 0, stream>>>(xdbl, ub, zb, W_dt, b_dt, A_log, D_par, yb);
    k_out_ln<<<512, 256, 0, stream>>>(yb, Woutb, gamma, beta, out);
}

// Round 2
// 226.218 us; speedup vs baseline: 1.0884x; 1.0884x over previous
//
#include <hip/hip_runtime.h>

typedef short bf16x8 __attribute__((ext_vector_type(8)));
typedef float f32x4 __attribute__((ext_vector_type(4)));

__device__ __forceinline__ unsigned short f2bf(float f) {
    unsigned int u = __builtin_bit_cast(unsigned int, f);
    u = (u + 0x7FFFu + ((u >> 16) & 1u)) >> 16;
    return (unsigned short)u;
}
__device__ __forceinline__ float bf2f(unsigned short h) {
    unsigned int u = ((unsigned int)h) << 16;
    return __builtin_bit_cast(float, u);
}

// ---------------------------------------------------------------------------
// Prep: permute x (B,T,N,Dm) -> Xbf rows r = bn*128+t, bn = b*64+n; fp32->bf16
__global__ __launch_bounds__(256) void k_prep_x(const float* __restrict__ x,
                                                unsigned int* __restrict__ Xbf2) {
    int tid = blockIdx.x * 256 + threadIdx.x;
    int c4 = tid & 63;      // group of 4 columns
    int r  = tid >> 6;      // output row
    int t = r & 127, bn = r >> 7;
    int n = bn & 63, b = bn >> 6;
    const float4 v = *((const float4*)(x + ((((size_t)(b * 128 + t)) * 64 + n) << 8)) + c4);
    uint2 o;
    o.x = (unsigned int)f2bf(v.x) | ((unsigned int)f2bf(v.y) << 16);
    o.y = (unsigned int)f2bf(v.z) | ((unsigned int)f2bf(v.w) << 16);
    *((uint2*)(Xbf2 + ((size_t)r << 7)) + c4) = o;
}

// Generic fp32 -> bf16 convert, 4 elements/thread (count % 4 == 0).
__global__ __launch_bounds__(256) void k_f2bf(const float* __restrict__ in,
                                              unsigned int* __restrict__ out, int n4) {
    int tid = blockIdx.x * 256 + threadIdx.x;
    if (tid >= n4) return;
    float4 v = ((const float4*)in)[tid];
    uint2 o;
    o.x = (unsigned int)f2bf(v.x) | ((unsigned int)f2bf(v.y) << 16);
    o.y = (unsigned int)f2bf(v.z) | ((unsigned int)f2bf(v.w) << 16);
    ((uint2*)out)[tid] = o;
}

// ---------------------------------------------------------------------------
// GEMM1: xz[16384 x 1024] = Xbf[16384 x 256] @ W_in_bf[1024 x 256]^T
__global__ __launch_bounds__(256, 2) void k_gemm1(const unsigned short* __restrict__ A,
                                                  const unsigned short* __restrict__ Bw,
                                                  unsigned short* __restrict__ xp,
                                                  unsigned short* __restrict__ z) {
    const int w = threadIdx.x >> 6, l = threadIdx.x & 63;
    const int lr = l & 15, lg = l >> 4;
    const int row0 = blockIdx.x * 256 + w * 64;
    const int n0 = blockIdx.y * 64;
    f32x4 acc[4][4] = {};
    for (int k0 = 0; k0 < 256; k0 += 32) {
        const int ka = k0 + lg * 8;
        bf16x8 a[4], b[4];
        #pragma unroll
        for (int mi = 0; mi < 4; ++mi)
            a[mi] = *(const bf16x8*)(A + (size_t)(row0 + mi * 16 + lr) * 256 + ka);
        #pragma unroll
        for (int ni = 0; ni < 4; ++ni)
            b[ni] = *(const bf16x8*)(Bw + (size_t)(n0 + ni * 16 + lr) * 256 + ka);
        #pragma unroll
        for (int mi = 0; mi < 4; ++mi)
            #pragma unroll
            for (int ni = 0; ni < 4; ++ni)
                acc[mi][ni] = __builtin_amdgcn_mfma_f32_16x16x32_bf16(a[mi], b[ni], acc[mi][ni], 0, 0, 0);
    }
    const bool isz = (n0 >= 512);
    unsigned short* dst = isz ? z : xp;
    const int c0 = isz ? (n0 - 512) : n0;
    #pragma unroll
    for (int mi = 0; mi < 4; ++mi)
        #pragma unroll
        for (int r = 0; r < 4; ++r) {
            const int row = row0 + mi * 16 + lg * 4 + r;
            #pragma unroll
            for (int ni = 0; ni < 4; ++ni)
                dst[(size_t)row * 512 + c0 + ni * 16 + lr] = f2bf(acc[mi][ni][r]);
        }
}

// ---------------------------------------------------------------------------
// Depthwise causal conv(4) + bias + SiLU, fully parallel over (bn, t, d-pair).
__global__ __launch_bounds__(256) void k_conv(const unsigned short* __restrict__ xp,
                                              const float* __restrict__ Wc,
                                              const float* __restrict__ bcv,
                                              unsigned int* __restrict__ ub2) {
    int tid = blockIdx.x * 256 + threadIdx.x;
    int d2 = tid & 255, r = tid >> 8;   // r = bn*128 + t
    int t = r & 127, bn = r >> 7;
    int d = d2 << 1;
    const unsigned short* src = xp + (size_t)bn * 65536 + d;
    f32x4 wa = *(const f32x4*)(Wc + d * 4);
    f32x4 wb = *(const f32x4*)(Wc + d * 4 + 4);
    float a0 = bcv[d], a1 = bcv[d + 1];
    #pragma unroll
    for (int k = 0; k < 4; ++k) {
        int tt = t - 3 + k;
        if (tt >= 0) {
            unsigned int p = *(const unsigned int*)(src + (size_t)tt * 512);
            a0 += bf2f((unsigned short)(p & 0xFFFFu)) * wa[k];
            a1 += bf2f((unsigned short)(p >> 16)) * wb[k];
        }
    }
    float u0 = a0 / (1.f + __expf(-a0));
    float u1 = a1 / (1.f + __expf(-a1));
    ub2[((size_t)bn * 65536 + (size_t)t * 512 + d) >> 1] =
        (unsigned int)f2bf(u0) | ((unsigned int)f2bf(u1) << 16);
}

// ---------------------------------------------------------------------------
// x_dbl[16384 x 48] = u_bf[16384 x 512] @ W_xproj_bf[48 x 512]^T  (fp32 out)
// wave = 16 rows x 48 cols; block = 4 waves = 64 rows; 256 blocks.
__global__ __launch_bounds__(256, 2) void k_xproj(const unsigned short* __restrict__ U,
                                                  const unsigned short* __restrict__ Wb,
                                                  float* __restrict__ xdbl) {
    const int w = threadIdx.x >> 6, l = threadIdx.x & 63;
    const int lr = l & 15, lg = l >> 4;
    const int row0 = blockIdx.x * 64 + w * 16;
    f32x4 acc[3] = {};
    for (int k0 = 0; k0 < 512; k0 += 32) {
        const int ka = k0 + lg * 8;
        bf16x8 a = *(const bf16x8*)(U + (size_t)(row0 + lr) * 512 + ka);
        bf16x8 b[3];
        #pragma unroll
        for (int ni = 0; ni < 3; ++ni)
            b[ni] = *(const bf16x8*)(Wb + (size_t)(ni * 16 + lr) * 512 + ka);
        #pragma unroll
        for (int ni = 0; ni < 3; ++ni)
            acc[ni] = __builtin_amdgcn_mfma_f32_16x16x32_bf16(a, b[ni], acc[ni], 0, 0, 0);
    }
    #pragma unroll
    for (int r = 0; r < 4; ++r) {
        const int row = row0 + lg * 4 + r;
        #pragma unroll
        for (int ni = 0; ni < 3; ++ni)
            xdbl[(size_t)row * 48 + ni * 16 + lr] = acc[ni][r];
    }
}

// ---------------------------------------------------------------------------
// dt = softplus(dt_raw @ W_dt^T + b_dt), fully parallel. One thread per (r, d).
// Output f16 (values are O(1); f16 mantissa => ~5e-4 rel err, negligible).
__global__ __launch_bounds__(256) void k_dt(const float* __restrict__ xdbl,
                                            const float* __restrict__ W_dt,
                                            const float* __restrict__ b_dt,
                                            _Float16* __restrict__ dtb) {
    int tid = blockIdx.x * 256 + threadIdx.x;
    int d = tid & 511, r = tid >> 9;
    const f32x4* xr = (const f32x4*)(xdbl + (size_t)r * 48);
    const f32x4* wd = (const f32x4*)(W_dt + d * 16);
    float dl = b_dt[d];
    #pragma unroll
    for (int k = 0; k < 4; ++k) {
        f32x4 xv = xr[k], wv = wd[k];
        dl += xv[0] * wv[0] + xv[1] * wv[1] + xv[2] * wv[2] + xv[3] * wv[3];
    }
    float dt = (dl > 20.f) ? dl : log1pf(__expf(dl));
    dtb[(size_t)r * 512 + d] = (_Float16)dt;
}

// ---------------------------------------------------------------------------
// Selective scan: 4 lanes per (bn,d), 4 states per lane. B,C staged in LDS.
// Block = 256 threads = 64 d's of one bn. Grid = 1024 blocks = 4096 waves.
__global__ __launch_bounds__(256) void k_scan(const _Float16* __restrict__ dtb,
                                              const float* __restrict__ xdbl,
                                              const unsigned short* __restrict__ ub,
                                              const unsigned short* __restrict__ zb,
                                              const float* __restrict__ A_log,
                                              const float* __restrict__ Dp,
                                              unsigned short* __restrict__ yb) {
    __shared__ float bc[128][32];  // [t][ B(0..15) | C(16..31) ]
    const int bn = blockIdx.x >> 3;
    const int d0 = (blockIdx.x & 7) * 64;
    {   // stage B,C for this bn: 128 rows x 32 floats
        const float* src = xdbl + (size_t)(bn * 128) * 48 + 16;
        #pragma unroll
        for (int k = 0; k < 4; ++k) {
            int li = threadIdx.x + k * 256;   // 0..1023
            int row = li >> 3, c4 = li & 7;
            f32x4 v = *(const f32x4*)(src + row * 48 + c4 * 4);
            *(f32x4*)(&bc[row][c4 * 4]) = v;
        }
    }
    __syncthreads();
    const int g = threadIdx.x >> 2;   // 0..63 -> d offset
    const int sub = threadIdx.x & 3;  // which state quad
    const int d = d0 + g;
    const int s0 = sub * 4;
    f32x4 al = *(const f32x4*)(A_log + d * 16 + s0);
    float A[4], h[4] = {0.f, 0.f, 0.f, 0.f};
    #pragma unroll
    for (int j = 0; j < 4; ++j) A[j] = -__expf(al[j]);
    const float dpar = Dp[d];
    const _Float16* dtp = dtb + (size_t)(bn * 128) * 512 + d;
    const unsigned short* up = ub + (size_t)bn * 65536 + d;
    const unsigned short* zp = zb + (size_t)bn * 65536 + d;
    unsigned short* yp = yb + (size_t)bn * 65536 + d;
    float dtv = (float)dtp[0];
    float uv = bf2f(up[0]), zv = bf2f(zp[0]);
    for (int t = 0; t < 128; ++t) {
        float dtn = 0.f, un = 0.f, zn = 0.f;
        if (t < 127) {
            dtn = (float)dtp[(t + 1) * 512];
            un = bf2f(up[(t + 1) * 512]);
            zn = bf2f(zp[(t + 1) * 512]);
        }
        f32x4 Bv = *(const f32x4*)(&bc[t][s0]);
        f32x4 Cv = *(const f32x4*)(&bc[t][16 + s0]);
        float du = dtv * uv;
        float y = 0.f;
        #pragma unroll
        for (int j = 0; j < 4; ++j) {
            float dA = __expf(dtv * A[j]);
            h[j] = h[j] * dA + du * Bv[j];
            y += h[j] * Cv[j];
        }
        y += __shfl_xor(y, 1);
        y += __shfl_xor(y, 2);
        if (sub == 0) {
            float yf = (y + uv * dpar) * (zv / (1.f + __expf(-zv)));
            yp[t * 512] = f2bf(yf);
        }
        dtv = dtn; uv = un; zv = zn;
    }
}

// ---------------------------------------------------------------------------
// out = LayerNorm( y_bf[16384 x 512] @ W_out_bf[256 x 512]^T ) with permuted store.
__global__ __launch_bounds__(256, 2) void k_out_ln(const unsigned short* __restrict__ Y,
                                                   const unsigned short* __restrict__ Wb,
                                                   const float* __restrict__ gamma,
                                                   const float* __restrict__ beta,
                                                   float* __restrict__ out) {
    __shared__ float s_sum[32], s_sq[32];
    const int w = threadIdx.x >> 6, l = threadIdx.x & 63;
    const int lr = l & 15, lg = l >> 4;
    const int row0 = blockIdx.x * 32;
    const int n0 = w * 64;
    f32x4 acc[2][4] = {};
    for (int k0 = 0; k0 < 512; k0 += 32) {
        const int ka = k0 + lg * 8;
        bf16x8 a[2], b[4];
        #pragma unroll
        for (int mi = 0; mi < 2; ++mi)
            a[mi] = *(const bf16x8*)(Y + (size_t)(row0 + mi * 16 + lr) * 512 + ka);
        #pragma unroll
        for (int ni = 0; ni < 4; ++ni)
            b[ni] = *(const bf16x8*)(Wb + (size_t)(n0 + ni * 16 + lr) * 512 + ka);
        #pragma unroll
        for (int mi = 0; mi < 2; ++mi)
            #pragma unroll
            for (int ni = 0; ni < 4; ++ni)
                acc[mi][ni] = __builtin_amdgcn_mfma_f32_16x16x32_bf16(a[mi], b[ni], acc[mi][ni], 0, 0, 0);
    }
    if (threadIdx.x < 32) { s_sum[threadIdx.x] = 0.f; s_sq[threadIdx.x] = 0.f; }
    __syncthreads();
    #pragma unroll
    for (int mi = 0; mi < 2; ++mi)
        #pragma unroll
        for (int r = 0; r < 4; ++r) {
            float s = 0.f, q = 0.f;
            #pragma unroll
            for (int ni = 0; ni < 4; ++ni) { float v = acc[mi][ni][r]; s += v; q += v * v; }
            #pragma unroll
            for (int m = 1; m < 16; m <<= 1) { s += __shfl_xor(s, m, 64); q += __shfl_xor(q, m, 64); }
            if (lr == 0) {
                atomicAdd(&s_sum[mi * 16 + lg * 4 + r], s);
                atomicAdd(&s_sq[mi * 16 + lg * 4 + r], q);
            }
        }
    __syncthreads();
    float g[4], be[4];
    #pragma unroll
    for (int ni = 0; ni < 4; ++ni) {
        g[ni] = gamma[n0 + ni * 16 + lr];
        be[ni] = beta[n0 + ni * 16 + lr];
    }
    #pragma unroll
    for (int mi = 0; mi < 2; ++mi)
        #pragma unroll
        for (int r = 0; r < 4; ++r) {
            const int rl = mi * 16 + lg * 4 + r;
            const int row = row0 + rl;
            const float mu = s_sum[rl] * (1.f / 256.f);
            const float var = s_sq[rl] * (1.f / 256.f) - mu * mu;
            const float rs = rsqrtf(var + 1e-5f);
            const int t = row & 127, bn = row >> 7;
            const int nn = bn & 63, bb = bn >> 6;
            float* orow = out + ((((size_t)(bb * 128 + t)) * 64 + nn) << 8);
            #pragma unroll
            for (int ni = 0; ni < 4; ++ni)
                orow[n0 + ni * 16 + lr] = (acc[mi][ni][r] - mu) * rs * g[ni] + be[ni];
        }
}

// ---------------------------------------------------------------------------
extern "C" void kernel_launch(void* const* d_in, const int* in_sizes, int n_in,
                              void* d_out, int out_size, void* d_ws, size_t ws_size,
                              hipStream_t stream) {
    const float* x      = (const float*)d_in[0];
    const float* W_in   = (const float*)d_in[1];
    const float* W_conv = (const float*)d_in[2];
    const float* b_conv = (const float*)d_in[3];
    const float* W_xprj = (const float*)d_in[4];
    const float* W_dt   = (const float*)d_in[5];
    const float* b_dt   = (const float*)d_in[6];
    const float* A_log  = (const float*)d_in[7];
    const float* D_par  = (const float*)d_in[8];
    const float* W_out  = (const float*)d_in[9];
    const float* gamma  = (const float*)d_in[10];
    const float* beta   = (const float*)d_in[11];
    float* out = (float*)d_out;

    char* ws = (char*)d_ws;
    size_t off = 0;
    auto alloc = [&](size_t bytes) -> void* {
        void* p = ws + off;
        off += (bytes + 255) & ~(size_t)255;
        return p;
    };
    // --- overlay region: dead after k_xproj; dtb aliases it ---
    unsigned short* Xbf   = (unsigned short*)alloc(16384ull * 256 * 2);  // 8.4 MB
    unsigned short* Winb  = (unsigned short*)alloc(1024ull * 256 * 2);
    unsigned short* Wxpb  = (unsigned short*)alloc(48ull * 512 * 2);
    unsigned short* xp    = (unsigned short*)alloc(16384ull * 512 * 2);  // 16.8 MB
    // --- live to the end ---
    unsigned short* Woutb = (unsigned short*)alloc(256ull * 512 * 2);
    unsigned short* zb    = (unsigned short*)alloc(16384ull * 512 * 2);
    unsigned short* ub    = (unsigned short*)alloc(16384ull * 512 * 2);
    float*          xdbl  = (float*)alloc(16384ull * 48 * 4);
    unsigned short* yb    = (unsigned short*)alloc(16384ull * 512 * 2);
    _Float16*       dtb   = (_Float16*)(ws);  // 16.8 MB alias over Xbf..xp (25.7 MB dead)
    if (off > ws_size) return;

    k_prep_x<<<4096, 256, 0, stream>>>(x, (unsigned int*)Xbf);
    k_f2bf<<<256, 256, 0, stream>>>(W_in, (unsigned int*)Winb, 65536);
    k_f2bf<<<24, 256, 0, stream>>>(W_xprj, (unsigned int*)Wxpb, 6144);
    k_f2bf<<<128, 256, 0, stream>>>(W_out, (unsigned int*)Woutb, 32768);
    k_gemm1<<<dim3(64, 16), 256, 0, stream>>>(Xbf, Winb, xp, zb);
    k_conv<<<16384, 256, 0, stream>>>(xp, W_conv, b_conv, (unsigned int*)ub);
    k_xproj<<<256, 256, 0, stream>>>(ub, Wxpb, xdbl);
    k_dt<<<32768, 256, 0, stream>>>(xdbl, W_dt, b_dt, dtb);
    k_scan<<<1024, 256, 0, stream>>>(dtb, xdbl, ub, zb, A_log, D_par, yb);
    k_out_ln<<<512, 256, 0, stream>>>(yb, Woutb, gamma, beta, out);
}